// Round 1
// baseline (9385.147 us; speedup 1.0000x reference)
//
#include <hip/hip_runtime.h>
#include <math.h>

#define N_NODES 100000
#define N_EDGES 1600000

__device__ __forceinline__ float elu_f(float v) {
    return v > 0.0f ? v : (expf(v) - 1.0f);
}

// H[N, FO] = act(X)[N, FI] @ W[FO, FI]^T + b[FO]
// Block: 256 threads, RPB = 256/FO rows per block. X rows staged in LDS
// (ELU fused at staging when ELU_IN), W read as float4 from L2 (W <= 128KB).
template<int FI, int FO, bool ELU_IN>
__global__ __launch_bounds__(256) void linear_kernel(
    const float* __restrict__ X, const float* __restrict__ W,
    const float* __restrict__ b, float* __restrict__ H)
{
    constexpr int RPB = 256 / FO;       // 2 for FO=128, 4 for FO=64
    constexpr int K4  = FI / 4;
    __shared__ float4 xs[RPB * K4];

    const int tid  = threadIdx.x;
    const int row0 = blockIdx.x * RPB;

    // Stage RPB rows of X into LDS, fuse input activation.
    constexpr int NV = RPB * K4;
    for (int i = tid; i < NV; i += 256) {
        const int r    = i / K4;
        const int k4   = i % K4;
        const int grow = row0 + r;
        float4 v = make_float4(0.f, 0.f, 0.f, 0.f);
        if (grow < N_NODES) {
            v = reinterpret_cast<const float4*>(X + (size_t)grow * FI)[k4];
            if (ELU_IN) {
                v.x = elu_f(v.x); v.y = elu_f(v.y);
                v.z = elu_f(v.z); v.w = elu_f(v.w);
            }
        }
        xs[i] = v;
    }
    __syncthreads();

    const int r    = tid / FO;
    const int c    = tid % FO;
    const int grow = row0 + r;

    float acc = b[c];
    const float4* __restrict__ Wv = reinterpret_cast<const float4*>(W) + (size_t)c * K4;
    const float4* xv = xs + r * K4;
    #pragma unroll
    for (int k4 = 0; k4 < K4; ++k4) {
        const float4 w4 = Wv[k4];
        const float4 x4 = xv[k4];
        acc += x4.x * w4.x + x4.y * w4.y + x4.z * w4.z + x4.w * w4.w;
    }
    if (grow < N_NODES) H[(size_t)grow * FO + c] = acc;
}

// A[src[e]] += H[dst[e]] * ew[e]   (F = 4*F4 features)
// One edge handled by F4 threads, each doing a float4 -> 4 atomicAdds.
template<int F4>
__global__ __launch_bounds__(256) void scatter_kernel(
    const float* __restrict__ H, const int* __restrict__ src,
    const int* __restrict__ dst, const float* __restrict__ ew,
    float* __restrict__ A)
{
    const long long t = (long long)blockIdx.x * 256 + threadIdx.x;
    const int e = (int)(t / F4);
    const int j = (int)(t % F4);
    if (e >= N_EDGES) return;

    const int   d = dst[e];
    const int   s = src[e];
    const float w = ew[e];

    const float4 v = reinterpret_cast<const float4*>(H + (size_t)d * (F4 * 4))[j];
    float* __restrict__ o = A + (size_t)s * (F4 * 4) + j * 4;
    atomicAdd(o + 0, v.x * w);
    atomicAdd(o + 1, v.y * w);
    atomicAdd(o + 2, v.z * w);
    atomicAdd(o + 3, v.w * w);
}

extern "C" void kernel_launch(void* const* d_in, const int* in_sizes, int n_in,
                              void* d_out, int out_size, void* d_ws, size_t ws_size,
                              hipStream_t stream) {
    const float* x   = (const float*)d_in[0];
    const int*   src = (const int*)  d_in[1];
    const int*   dst = (const int*)  d_in[2];
    const float* ew  = (const float*)d_in[3];
    const float* W1  = (const float*)d_in[4];
    const float* b1  = (const float*)d_in[5];
    const float* W2  = (const float*)d_in[6];
    const float* b2  = (const float*)d_in[7];
    const float* W3  = (const float*)d_in[8];
    const float* b3  = (const float*)d_in[9];
    float* out  = (float*)d_out;
    float* buf0 = (float*)d_ws;                         // 100000*128 f32 = 51.2 MB
    float* buf1 = buf0 + (size_t)N_NODES * 128;         // another 51.2 MB

    const int gemm128_blocks = N_NODES / 2;             // RPB=2
    const int gemm64_blocks  = N_NODES / 4;             // RPB=4
    const int sc128_blocks   = (N_EDGES * 32 + 255) / 256;
    const int sc64_blocks    = (N_EDGES * 16 + 255) / 256;

    // ---- Layer 1: H1 = x @ W1^T + b1 ; A1 = scatter(H1) ----
    linear_kernel<256, 128, false><<<gemm128_blocks, 256, 0, stream>>>(x, W1, b1, buf0);
    hipMemsetAsync(buf1, 0, (size_t)N_NODES * 128 * sizeof(float), stream);
    scatter_kernel<32><<<sc128_blocks, 256, 0, stream>>>(buf0, src, dst, ew, buf1);

    // ---- Layer 2: H2 = elu(A1) @ W2^T + b2 ; A2 = scatter(H2) ----
    linear_kernel<128, 128, true><<<gemm128_blocks, 256, 0, stream>>>(buf1, W2, b2, buf0);
    hipMemsetAsync(buf1, 0, (size_t)N_NODES * 128 * sizeof(float), stream);
    scatter_kernel<32><<<sc128_blocks, 256, 0, stream>>>(buf0, src, dst, ew, buf1);

    // ---- Layer 3: H3 = elu(A2) @ W3^T + b3 ; out = scatter(H3), no act ----
    linear_kernel<128, 64, true><<<gemm64_blocks, 256, 0, stream>>>(buf1, W3, b3, buf0);
    hipMemsetAsync(out, 0, (size_t)N_NODES * 64 * sizeof(float), stream);
    scatter_kernel<16><<<sc64_blocks, 256, 0, stream>>>(buf0, src, dst, ew, out);
}

// Round 4
// 1418.817 us; speedup vs baseline: 6.6148x; 6.6148x over previous
//
#include <hip/hip_runtime.h>
#include <hip/hip_bf16.h>
#include <math.h>

#define N_NODES 100000
#define N_EDGES 1600000

__device__ __forceinline__ float elu_f(float v) {
    return v > 0.0f ? v : (__expf(v) - 1.0f);
}

// ---------------------------------------------------------------------------
// CSR build: deg counts -> segment alloc (wave scan + 1 atomic/wave) -> fill.
// Segment order across nodes is arbitrary (alloc order); irrelevant for gather.
// ---------------------------------------------------------------------------
__global__ __launch_bounds__(256) void count_kernel(
    const int* __restrict__ src, int* __restrict__ deg)
{
    const int e = blockIdx.x * 256 + threadIdx.x;
    if (e < N_EDGES) atomicAdd(&deg[src[e]], 1);
}

__global__ __launch_bounds__(256) void alloc_kernel(
    const int* __restrict__ deg, int* __restrict__ off,
    int* __restrict__ cur, int* __restrict__ total)
{
    const int n    = blockIdx.x * 256 + threadIdx.x;
    const int lane = threadIdx.x & 63;
    const int v    = (n < N_NODES) ? deg[n] : 0;

    // inclusive wave scan of v
    int inc = v;
    #pragma unroll
    for (int s = 1; s < 64; s <<= 1) {
        int t = __shfl_up(inc, s);
        if (lane >= s) inc += t;
    }
    const int wtot = __shfl(inc, 63);
    int base = 0;
    if (lane == 63) base = atomicAdd(total, wtot);
    base = __shfl(base, 63);

    if (n < N_NODES) {
        const int o = base + inc - v;   // exclusive within wave + global base
        off[n] = o;
        cur[n] = o;                      // fill cursor; ends at off[n]+deg[n]
    }
}

__global__ __launch_bounds__(256) void fill_kernel(
    const int* __restrict__ src, const int* __restrict__ dst,
    const float* __restrict__ ew, int* __restrict__ cur,
    int* __restrict__ sdst, float* __restrict__ sw)
{
    const int e = blockIdx.x * 256 + threadIdx.x;
    if (e >= N_EDGES) return;
    const int p = atomicAdd(&cur[src[e]], 1);
    sdst[p] = dst[e];
    sw[p]   = ew[e];
}

// ---------------------------------------------------------------------------
// Linear: H_bf16[N, FO] = act(X)[N, FI] @ W[FO, FI]^T + b.
// 256 threads, RPB rows/block, 4 outputs per thread (W-row reused 4x).
// ---------------------------------------------------------------------------
template<int FI, int FO, int RPB, bool ELU_IN>
__global__ __launch_bounds__(256) void linear_kernel(
    const float* __restrict__ X, const float* __restrict__ W,
    const float* __restrict__ b, __hip_bfloat16* __restrict__ H)
{
    constexpr int K4     = FI / 4;
    constexpr int GROUPS = 256 / FO;         // 2 (FO=128) or 4 (FO=64)
    constexpr int RPT    = RPB / GROUPS;     // 4
    __shared__ float4 xs[RPB][K4];

    const int tid  = threadIdx.x;
    const int row0 = blockIdx.x * RPB;       // grids divide N_NODES exactly

    for (int i = tid; i < RPB * K4; i += 256) {
        const int r = i / K4, k = i % K4;
        float4 v = reinterpret_cast<const float4*>(X + (size_t)(row0 + r) * FI)[k];
        if (ELU_IN) {
            v.x = elu_f(v.x); v.y = elu_f(v.y);
            v.z = elu_f(v.z); v.w = elu_f(v.w);
        }
        xs[r][k] = v;
    }
    __syncthreads();

    const int c = tid % FO;
    const int g = tid / FO;

    float acc[RPT];
    const float bias = b[c];
    #pragma unroll
    for (int j = 0; j < RPT; ++j) acc[j] = bias;

    const float4* __restrict__ Wv = reinterpret_cast<const float4*>(W) + (size_t)c * K4;
    #pragma unroll 4
    for (int k4 = 0; k4 < K4; ++k4) {
        const float4 w4 = Wv[k4];
        #pragma unroll
        for (int j = 0; j < RPT; ++j) {
            const float4 x4 = xs[g * RPT + j][k4];
            acc[j] += x4.x * w4.x + x4.y * w4.y + x4.z * w4.z + x4.w * w4.w;
        }
    }
    #pragma unroll
    for (int j = 0; j < RPT; ++j) {
        const int gr = row0 + g * RPT + j;
        H[(size_t)gr * FO + c] = __float2bfloat16(acc[j]);
    }
}

// ---------------------------------------------------------------------------
// Gather-aggregate over CSR: A[n,:] = sum_{e in seg(n)} H[sdst[e],:] * sw[e].
// One wave per node; F=128 -> 2 feats/lane (uint load), F=64 -> 1 feat/lane.
// ---------------------------------------------------------------------------
template<int F>
__global__ __launch_bounds__(256) void gather_kernel(
    const __hip_bfloat16* __restrict__ H, const int* __restrict__ off,
    const int* __restrict__ end, const int* __restrict__ sdst,
    const float* __restrict__ sw, float* __restrict__ A)
{
    const int node = (blockIdx.x * 256 + threadIdx.x) >> 6;   // wave per node
    const int lane = threadIdx.x & 63;

    const int beg = off[node];
    const int fin = end[node];

    if (F == 128) {
        float acc0 = 0.f, acc1 = 0.f;
        const unsigned* __restrict__ Hu =
            reinterpret_cast<const unsigned*>(H) + lane;      // +d*64 per row
        for (int e = beg; e < fin; ++e) {
            const int   d = sdst[e];
            const float w = sw[e];
            const unsigned v = Hu[(size_t)d * 64];
            acc0 = fmaf(__uint_as_float(v << 16), w, acc0);
            acc1 = fmaf(__uint_as_float(v & 0xffff0000u), w, acc1);
        }
        float2 o; o.x = acc0; o.y = acc1;
        *reinterpret_cast<float2*>(A + (size_t)node * 128 + lane * 2) = o;
    } else {
        float acc = 0.f;
        const unsigned short* __restrict__ Hs =
            reinterpret_cast<const unsigned short*>(H) + lane;
        for (int e = beg; e < fin; ++e) {
            const int   d = sdst[e];
            const float w = sw[e];
            const unsigned v = Hs[(size_t)d * 64];
            acc = fmaf(__uint_as_float(v << 16), w, acc);
        }
        A[(size_t)node * 64 + lane] = acc;
    }
}

extern "C" void kernel_launch(void* const* d_in, const int* in_sizes, int n_in,
                              void* d_out, int out_size, void* d_ws, size_t ws_size,
                              hipStream_t stream) {
    const float* x   = (const float*)d_in[0];
    const int*   src = (const int*)  d_in[1];
    const int*   dst = (const int*)  d_in[2];
    const float* ew  = (const float*)d_in[3];
    const float* W1  = (const float*)d_in[4];
    const float* b1  = (const float*)d_in[5];
    const float* W2  = (const float*)d_in[6];
    const float* b2  = (const float*)d_in[7];
    const float* W3  = (const float*)d_in[8];
    const float* b3  = (const float*)d_in[9];
    float* out = (float*)d_out;

    // ---- workspace layout (~90.8 MB) ----
    float*          A    = (float*)d_ws;                                 // 51.2 MB
    __hip_bfloat16* Hb   = (__hip_bfloat16*)(A + (size_t)N_NODES * 128); // 25.6 MB
    int*            sdst = (int*)  (Hb + (size_t)N_NODES * 128);         // 6.4 MB
    float*          sw   = (float*)(sdst + N_EDGES);                     // 6.4 MB
    int*            deg  = (int*)  (sw + N_EDGES);                       // 400 KB
    int*            off  = deg + N_NODES;
    int*            cur  = off + N_NODES;
    int*            tot  = cur + N_NODES;                                // 4 B

    const int eblocks = (N_EDGES + 255) / 256;   // 6250
    const int nblocks = (N_NODES + 255) / 256;   // 391

    // ---- CSR build (reused by all 3 layers) ----
    hipMemsetAsync(deg, 0, ((size_t)3 * N_NODES + 1) * sizeof(int), stream);
    count_kernel<<<eblocks, 256, 0, stream>>>(src, deg);
    alloc_kernel<<<nblocks, 256, 0, stream>>>(deg, off, cur, tot);
    fill_kernel<<<eblocks, 256, 0, stream>>>(src, dst, ew, cur, sdst, sw);
    // after fill: cur[n] == off[n] + deg[n] == segment end

    // ---- Layer 1 ----
    linear_kernel<256, 128, 8, false><<<N_NODES / 8, 256, 0, stream>>>(x, W1, b1, Hb);
    gather_kernel<128><<<N_NODES / 4, 256, 0, stream>>>(Hb, off, cur, sdst, sw, A);

    // ---- Layer 2 ----
    linear_kernel<128, 128, 8, true><<<N_NODES / 8, 256, 0, stream>>>(A, W2, b2, Hb);
    gather_kernel<128><<<N_NODES / 4, 256, 0, stream>>>(Hb, off, cur, sdst, sw, A);

    // ---- Layer 3 (no activation after aggregate) ----
    linear_kernel<128, 64, 16, true><<<N_NODES / 16, 256, 0, stream>>>(A, W3, b3, Hb);
    gather_kernel<64><<<N_NODES / 4, 256, 0, stream>>>(Hb, off, cur, sdst, sw, out);
}

// Round 7
// 873.709 us; speedup vs baseline: 10.7417x; 1.6239x over previous
//
#include <hip/hip_runtime.h>
#include <hip/hip_bf16.h>
#include <math.h>

#define N_NODES 100000
#define N_EDGES 1600000

typedef __attribute__((ext_vector_type(8))) short bf16x8;
typedef __attribute__((ext_vector_type(4))) float f32x4;

__device__ __forceinline__ float elu_f(float v) {
    return v > 0.0f ? v : (__expf(v) - 1.0f);
}
// f32 -> bf16 bits, round-to-nearest-even
__device__ __forceinline__ short f2bf(float f) {
    unsigned u = __float_as_uint(f);
    u += 0x7fffu + ((u >> 16) & 1u);
    return (short)(u >> 16);
}

// ---------------------------------------------------------------------------
// CSR build: deg counts -> segment alloc (wave scan + 1 atomic/wave) -> fill.
// ---------------------------------------------------------------------------
__global__ __launch_bounds__(256) void count_kernel(
    const int* __restrict__ src, int* __restrict__ deg)
{
    const int e = blockIdx.x * 256 + threadIdx.x;
    if (e < N_EDGES) atomicAdd(&deg[src[e]], 1);
}

__global__ __launch_bounds__(256) void alloc_kernel(
    const int* __restrict__ deg, int* __restrict__ off,
    int* __restrict__ cur, int* __restrict__ total)
{
    const int n    = blockIdx.x * 256 + threadIdx.x;
    const int lane = threadIdx.x & 63;
    const int v    = (n < N_NODES) ? deg[n] : 0;

    int inc = v;
    #pragma unroll
    for (int s = 1; s < 64; s <<= 1) {
        int t = __shfl_up(inc, s);
        if (lane >= s) inc += t;
    }
    const int wtot = __shfl(inc, 63);
    int base = 0;
    if (lane == 63) base = atomicAdd(total, wtot);
    base = __shfl(base, 63);

    if (n < N_NODES) {
        const int o = base + inc - v;
        off[n] = o;
        cur[n] = o;
    }
}

__global__ __launch_bounds__(256) void fill_kernel(
    const int* __restrict__ src, const int* __restrict__ dst,
    const float* __restrict__ ew, int* __restrict__ cur,
    int* __restrict__ sdst, float* __restrict__ sw)
{
    const int e = blockIdx.x * 256 + threadIdx.x;
    if (e >= N_EDGES) return;
    const int p = atomicAdd(&cur[src[e]], 1);
    sdst[p] = dst[e];
    sw[p]   = ew[e];
}

// ---------------------------------------------------------------------------
// Weight conversion f32 -> bf16 (once per call; 57344 elements total).
// ---------------------------------------------------------------------------
__global__ __launch_bounds__(256) void convw_kernel(
    const float* __restrict__ W1, const float* __restrict__ W2,
    const float* __restrict__ W3, unsigned short* __restrict__ Wb1,
    unsigned short* __restrict__ Wb2, unsigned short* __restrict__ Wb3)
{
    const int i = blockIdx.x * 256 + threadIdx.x;
    if (i < 32768)      Wb1[i]         = (unsigned short)f2bf(W1[i]);
    else if (i < 49152) Wb2[i - 32768] = (unsigned short)f2bf(W2[i - 32768]);
    else if (i < 57344) Wb3[i - 49152] = (unsigned short)f2bf(W3[i - 49152]);
}

// ---------------------------------------------------------------------------
// MFMA linear: H_bf16[N, FO] = X[N, K] @ Wb[FO, K]^T + bias.
// 4 waves/block, each wave owns 32 rows x FO cols. No LDS: W fragments come
// straight from global (W <= 64KB bf16, L1/L2-resident). NT fragment layout:
// both A and B frags are lane-contiguous bf16x8 at [(l&15)][(l>>4)*8 + j].
// C/D: col = lane&15, row = (lane>>4)*4 + reg   (guide §3, m89/m91).
// ---------------------------------------------------------------------------
template<int K, int FO, bool A_F32>
__global__ __launch_bounds__(256) void linear_mfma(
    const void* __restrict__ Xin, const unsigned short* __restrict__ Wb,
    const float* __restrict__ bias, unsigned short* __restrict__ H)
{
    constexpr int CT = FO / 16;   // col tiles
    constexpr int KK = K / 32;    // k chunks
    const int tid  = threadIdx.x;
    const int wid  = tid >> 6;
    const int lane = tid & 63;
    const int l15  = lane & 15;
    const int lg   = lane >> 4;
    const int row0 = blockIdx.x * 128 + wid * 32;
    const int kbase = lg * 8;

    f32x4 acc[2][CT];
    #pragma unroll
    for (int c = 0; c < CT; ++c) {
        const float bv = bias[c * 16 + l15];
        #pragma unroll
        for (int r = 0; r < 2; ++r) acc[r][c] = (f32x4){bv, bv, bv, bv};
    }

    #pragma unroll
    for (int kk = 0; kk < KK; ++kk) {
        bf16x8 a[2];
        #pragma unroll
        for (int r = 0; r < 2; ++r) {
            int row = row0 + r * 16 + l15;
            row = row < N_NODES ? row : N_NODES - 1;   // clamp: loads stay in-bounds
            if (A_F32) {
                const float* ap = (const float*)Xin + (size_t)row * K + kk * 32 + kbase;
                const float4 x0 = ((const float4*)ap)[0];
                const float4 x1 = ((const float4*)ap)[1];
                bf16x8 t;
                t[0] = f2bf(x0.x); t[1] = f2bf(x0.y); t[2] = f2bf(x0.z); t[3] = f2bf(x0.w);
                t[4] = f2bf(x1.x); t[5] = f2bf(x1.y); t[6] = f2bf(x1.z); t[7] = f2bf(x1.w);
                a[r] = t;
            } else {
                a[r] = *(const bf16x8*)((const unsigned short*)Xin +
                                        (size_t)row * K + kk * 32 + kbase);
            }
        }
        #pragma unroll
        for (int c = 0; c < CT; ++c) {
            const bf16x8 bfr = *(const bf16x8*)(Wb + (size_t)(c * 16 + l15) * K +
                                                kk * 32 + kbase);
            #pragma unroll
            for (int r = 0; r < 2; ++r)
                acc[r][c] = __builtin_amdgcn_mfma_f32_16x16x32_bf16(
                    a[r], bfr, acc[r][c], 0, 0, 0);
        }
    }

    #pragma unroll
    for (int r = 0; r < 2; ++r) {
        const int rbase = row0 + r * 16 + lg * 4;
        #pragma unroll
        for (int j = 0; j < 4; ++j) {
            const int row = rbase + j;
            if (row < N_NODES) {
                #pragma unroll
                for (int c = 0; c < CT; ++c)
                    H[(size_t)row * FO + c * 16 + l15] =
                        (unsigned short)f2bf(acc[r][c][j]);
            }
        }
    }
}

// ---------------------------------------------------------------------------
// Gather-aggregate over CSR: out[n,:] = sum_{e in seg(n)} H[sdst[e],:] * sw[e].
// One wave per node. Layers 1-2: fuse ELU, emit bf16 (feeds next GEMM).
// Layer 3: no act, f32 out.
// ---------------------------------------------------------------------------
template<int F, bool ELU_OUT, bool OUT_BF16>
__global__ __launch_bounds__(256) void gather_kernel(
    const unsigned short* __restrict__ H, const int* __restrict__ off,
    const int* __restrict__ end, const int* __restrict__ sdst,
    const float* __restrict__ sw, void* __restrict__ out)
{
    const int node = (blockIdx.x * 256 + threadIdx.x) >> 6;
    const int lane = threadIdx.x & 63;
    const int beg = off[node];
    const int fin = end[node];

    if (F == 128) {
        float acc0 = 0.f, acc1 = 0.f;
        const unsigned* __restrict__ Hu = (const unsigned*)H + lane;
        for (int e = beg; e < fin; ++e) {
            const int   d = sdst[e];
            const float w = sw[e];
            const unsigned v = Hu[(size_t)d * 64];
            acc0 = fmaf(__uint_as_float(v << 16), w, acc0);
            acc1 = fmaf(__uint_as_float(v & 0xffff0000u), w, acc1);
        }
        if (ELU_OUT) { acc0 = elu_f(acc0); acc1 = elu_f(acc1); }
        if (OUT_BF16) {
            const unsigned lo = (unsigned short)f2bf(acc0);
            const unsigned hi = (unsigned short)f2bf(acc1);
            ((unsigned*)out)[(size_t)node * 64 + lane] = lo | (hi << 16);
        } else {
            float2 o; o.x = acc0; o.y = acc1;
            ((float2*)out)[(size_t)node * 64 + lane] = o;
        }
    } else {
        float acc = 0.f;
        const unsigned short* __restrict__ Hs = H + lane;
        for (int e = beg; e < fin; ++e) {
            const int   d = sdst[e];
            const float w = sw[e];
            const unsigned v = Hs[(size_t)d * 64];
            acc = fmaf(__uint_as_float(v << 16), w, acc);
        }
        ((float*)out)[(size_t)node * 64 + lane] = acc;
    }
}

extern "C" void kernel_launch(void* const* d_in, const int* in_sizes, int n_in,
                              void* d_out, int out_size, void* d_ws, size_t ws_size,
                              hipStream_t stream) {
    const float* x   = (const float*)d_in[0];
    const int*   src = (const int*)  d_in[1];
    const int*   dst = (const int*)  d_in[2];
    const float* ew  = (const float*)d_in[3];
    const float* W1  = (const float*)d_in[4];
    const float* b1  = (const float*)d_in[5];
    const float* W2  = (const float*)d_in[6];
    const float* b2  = (const float*)d_in[7];
    const float* W3  = (const float*)d_in[8];
    const float* b3  = (const float*)d_in[9];
    float* out = (float*)d_out;

    // ---- workspace layout (~65 MB) ----
    unsigned short* Hb  = (unsigned short*)d_ws;                 // 25.6 MB
    unsigned short* Ab  = Hb + (size_t)N_NODES * 128;            // 25.6 MB
    unsigned short* Wb1 = Ab + (size_t)N_NODES * 128;            // 64 KB
    unsigned short* Wb2 = Wb1 + 256 * 128;                       // 32 KB
    unsigned short* Wb3 = Wb2 + 128 * 128;                       // 16 KB
    int*   sdst = (int*)(Wb3 + 64 * 128);                        // 6.4 MB
    float* sw   = (float*)(sdst + N_EDGES);                      // 6.4 MB
    int*   deg  = (int*)(sw + N_EDGES);                          // 400 KB
    int*   off  = deg + N_NODES;
    int*   cur  = off + N_NODES;
    int*   tot  = cur + N_NODES;                                 // 4 B

    const int eblocks = (N_EDGES + 255) / 256;     // 6250
    const int nblocks = (N_NODES + 255) / 256;     // 391
    const int gblocks = (N_NODES + 127) / 128;     // 782 (GEMM)
    const int ablocks = N_NODES / 4;               // 25000 (gather)

    // ---- CSR build + weight conversion ----
    hipMemsetAsync(deg, 0, ((size_t)3 * N_NODES + 1) * sizeof(int), stream);
    count_kernel<<<eblocks, 256, 0, stream>>>(src, deg);
    alloc_kernel<<<nblocks, 256, 0, stream>>>(deg, off, cur, tot);
    fill_kernel<<<eblocks, 256, 0, stream>>>(src, dst, ew, cur, sdst, sw);
    convw_kernel<<<224, 256, 0, stream>>>(W1, W2, W3, Wb1, Wb2, Wb3);

    // ---- Layer 1 ----
    linear_mfma<256, 128, true><<<gblocks, 256, 0, stream>>>(x, Wb1, b1, Hb);
    gather_kernel<128, true, true><<<ablocks, 256, 0, stream>>>(Hb, off, cur, sdst, sw, Ab);

    // ---- Layer 2 ----
    linear_mfma<128, 128, false><<<gblocks, 256, 0, stream>>>(Ab, Wb2, b2, Hb);
    gather_kernel<128, true, true><<<ablocks, 256, 0, stream>>>(Hb, off, cur, sdst, sw, Ab);

    // ---- Layer 3 ----
    linear_mfma<128, 64, false><<<gblocks, 256, 0, stream>>>(Ab, Wb3, b3, Hb);
    gather_kernel<64, false, false><<<ablocks, 256, 0, stream>>>(Hb, off, cur, sdst, sw, out);
}

// Round 8
// 659.635 us; speedup vs baseline: 14.2278x; 1.3245x over previous
//
#include <hip/hip_runtime.h>
#include <hip/hip_bf16.h>
#include <math.h>

#define N_NODES 100000
#define N_EDGES 1600000

typedef __attribute__((ext_vector_type(8))) short bf16x8;
typedef __attribute__((ext_vector_type(4))) float f32x4;

__device__ __forceinline__ float elu_f(float v) {
    return v > 0.0f ? v : (__expf(v) - 1.0f);
}
// f32 -> bf16 bits, round-to-nearest-even
__device__ __forceinline__ short f2bf(float f) {
    unsigned u = __float_as_uint(f);
    u += 0x7fffu + ((u >> 16) & 1u);
    return (short)(u >> 16);
}

// ---------------------------------------------------------------------------
// CSR build: deg counts -> segment alloc (wave scan + 1 atomic/wave) -> fill.
// Edge records packed as int2{dst, bits(w)} so gather does 1 load per edge.
// ---------------------------------------------------------------------------
__global__ __launch_bounds__(256) void count_kernel(
    const int* __restrict__ src, int* __restrict__ deg)
{
    const int e = blockIdx.x * 256 + threadIdx.x;
    if (e < N_EDGES) atomicAdd(&deg[src[e]], 1);
}

__global__ __launch_bounds__(256) void alloc_kernel(
    const int* __restrict__ deg, int* __restrict__ off,
    int* __restrict__ cur, int* __restrict__ total)
{
    const int n    = blockIdx.x * 256 + threadIdx.x;
    const int lane = threadIdx.x & 63;
    const int v    = (n < N_NODES) ? deg[n] : 0;

    int inc = v;
    #pragma unroll
    for (int s = 1; s < 64; s <<= 1) {
        int t = __shfl_up(inc, s);
        if (lane >= s) inc += t;
    }
    const int wtot = __shfl(inc, 63);
    int base = 0;
    if (lane == 63) base = atomicAdd(total, wtot);
    base = __shfl(base, 63);

    if (n < N_NODES) {
        const int o = base + inc - v;
        off[n] = o;
        cur[n] = o;
    }
}

__global__ __launch_bounds__(256) void fill_kernel(
    const int* __restrict__ src, const int* __restrict__ dst,
    const float* __restrict__ ew, int* __restrict__ cur,
    int2* __restrict__ edges)
{
    const int e = blockIdx.x * 256 + threadIdx.x;
    if (e >= N_EDGES) return;
    const int p = atomicAdd(&cur[src[e]], 1);
    edges[p] = make_int2(dst[e], __float_as_int(ew[e]));
}

// ---------------------------------------------------------------------------
// Weight conversion f32 -> bf16 (once per call; 57344 elements total).
// ---------------------------------------------------------------------------
__global__ __launch_bounds__(256) void convw_kernel(
    const float* __restrict__ W1, const float* __restrict__ W2,
    const float* __restrict__ W3, unsigned short* __restrict__ Wb1,
    unsigned short* __restrict__ Wb2, unsigned short* __restrict__ Wb3)
{
    const int i = blockIdx.x * 256 + threadIdx.x;
    if (i < 32768)      Wb1[i]         = (unsigned short)f2bf(W1[i]);
    else if (i < 49152) Wb2[i - 32768] = (unsigned short)f2bf(W2[i - 32768]);
    else if (i < 57344) Wb3[i - 49152] = (unsigned short)f2bf(W3[i - 49152]);
}

// ---------------------------------------------------------------------------
// MFMA linear: H_bf16[N, FO] = X[N, K] @ Wb[FO, K]^T + bias.  (unchanged)
// ---------------------------------------------------------------------------
template<int K, int FO, bool A_F32>
__global__ __launch_bounds__(256) void linear_mfma(
    const void* __restrict__ Xin, const unsigned short* __restrict__ Wb,
    const float* __restrict__ bias, unsigned short* __restrict__ H)
{
    constexpr int CT = FO / 16;   // col tiles
    constexpr int KK = K / 32;    // k chunks
    const int tid  = threadIdx.x;
    const int wid  = tid >> 6;
    const int lane = tid & 63;
    const int l15  = lane & 15;
    const int lg   = lane >> 4;
    const int row0 = blockIdx.x * 128 + wid * 32;
    const int kbase = lg * 8;

    f32x4 acc[2][CT];
    #pragma unroll
    for (int c = 0; c < CT; ++c) {
        const float bv = bias[c * 16 + l15];
        #pragma unroll
        for (int r = 0; r < 2; ++r) acc[r][c] = (f32x4){bv, bv, bv, bv};
    }

    #pragma unroll
    for (int kk = 0; kk < KK; ++kk) {
        bf16x8 a[2];
        #pragma unroll
        for (int r = 0; r < 2; ++r) {
            int row = row0 + r * 16 + l15;
            row = row < N_NODES ? row : N_NODES - 1;   // clamp: loads stay in-bounds
            if (A_F32) {
                const float* ap = (const float*)Xin + (size_t)row * K + kk * 32 + kbase;
                const float4 x0 = ((const float4*)ap)[0];
                const float4 x1 = ((const float4*)ap)[1];
                bf16x8 t;
                t[0] = f2bf(x0.x); t[1] = f2bf(x0.y); t[2] = f2bf(x0.z); t[3] = f2bf(x0.w);
                t[4] = f2bf(x1.x); t[5] = f2bf(x1.y); t[6] = f2bf(x1.z); t[7] = f2bf(x1.w);
                a[r] = t;
            } else {
                a[r] = *(const bf16x8*)((const unsigned short*)Xin +
                                        (size_t)row * K + kk * 32 + kbase);
            }
        }
        #pragma unroll
        for (int c = 0; c < CT; ++c) {
            const bf16x8 bfr = *(const bf16x8*)(Wb + (size_t)(c * 16 + l15) * K +
                                                kk * 32 + kbase);
            #pragma unroll
            for (int r = 0; r < 2; ++r)
                acc[r][c] = __builtin_amdgcn_mfma_f32_16x16x32_bf16(
                    a[r], bfr, acc[r][c], 0, 0, 0);
        }
    }

    #pragma unroll
    for (int r = 0; r < 2; ++r) {
        const int rbase = row0 + r * 16 + lg * 4;
        #pragma unroll
        for (int j = 0; j < 4; ++j) {
            const int row = rbase + j;
            if (row < N_NODES) {
                #pragma unroll
                for (int c = 0; c < CT; ++c)
                    H[(size_t)row * FO + c * 16 + l15] =
                        (unsigned short)f2bf(acc[r][c][j]);
            }
        }
    }
}

// ---------------------------------------------------------------------------
// Gather-aggregate over CSR: out[n,:] = sum_{e in seg(n)} H[edges[e].dst,:] * w.
// One wave per node. Unrolled x8: 8 independent H-row loads in flight to hide
// L2/L3 fetch latency (the round-7 profile showed latency-bound, 1 load deep).
// ---------------------------------------------------------------------------
template<int F, bool ELU_OUT, bool OUT_BF16>
__global__ __launch_bounds__(256) void gather_kernel(
    const unsigned short* __restrict__ H, const int* __restrict__ off,
    const int* __restrict__ end, const int2* __restrict__ edges,
    void* __restrict__ out)
{
    const int node = (blockIdx.x * 256 + threadIdx.x) >> 6;
    const int lane = threadIdx.x & 63;
    const int beg = off[node];
    const int fin = end[node];

    if (F == 128) {
        float acc0 = 0.f, acc1 = 0.f;
        const unsigned* __restrict__ Hu = (const unsigned*)H + lane;
        int e = beg;
        for (; e + 8 <= fin; e += 8) {
            int2 ed[8];
            #pragma unroll
            for (int u = 0; u < 8; ++u) ed[u] = edges[e + u];
            unsigned v[8];
            #pragma unroll
            for (int u = 0; u < 8; ++u) v[u] = Hu[(size_t)ed[u].x * 64];
            #pragma unroll
            for (int u = 0; u < 8; ++u) {
                const float w = __int_as_float(ed[u].y);
                acc0 = fmaf(__uint_as_float(v[u] << 16), w, acc0);
                acc1 = fmaf(__uint_as_float(v[u] & 0xffff0000u), w, acc1);
            }
        }
        for (; e < fin; ++e) {
            const int2 ed = edges[e];
            const float w = __int_as_float(ed.y);
            const unsigned v = Hu[(size_t)ed.x * 64];
            acc0 = fmaf(__uint_as_float(v << 16), w, acc0);
            acc1 = fmaf(__uint_as_float(v & 0xffff0000u), w, acc1);
        }
        if (ELU_OUT) { acc0 = elu_f(acc0); acc1 = elu_f(acc1); }
        if (OUT_BF16) {
            const unsigned lo = (unsigned short)f2bf(acc0);
            const unsigned hi = (unsigned short)f2bf(acc1);
            ((unsigned*)out)[(size_t)node * 64 + lane] = lo | (hi << 16);
        } else {
            float2 o; o.x = acc0; o.y = acc1;
            ((float2*)out)[(size_t)node * 64 + lane] = o;
        }
    } else {
        float acc = 0.f;
        const unsigned short* __restrict__ Hs = H + lane;
        int e = beg;
        for (; e + 8 <= fin; e += 8) {
            int2 ed[8];
            #pragma unroll
            for (int u = 0; u < 8; ++u) ed[u] = edges[e + u];
            unsigned v[8];
            #pragma unroll
            for (int u = 0; u < 8; ++u) v[u] = Hs[(size_t)ed[u].x * 64];
            #pragma unroll
            for (int u = 0; u < 8; ++u) {
                const float w = __int_as_float(ed[u].y);
                acc = fmaf(__uint_as_float(v[u] << 16), w, acc);
            }
        }
        for (; e < fin; ++e) {
            const int2 ed = edges[e];
            const float w = __int_as_float(ed.y);
            const unsigned v = Hs[(size_t)ed.x * 64];
            acc = fmaf(__uint_as_float(v << 16), w, acc);
        }
        ((float*)out)[(size_t)node * 64 + lane] = acc;
    }
}

extern "C" void kernel_launch(void* const* d_in, const int* in_sizes, int n_in,
                              void* d_out, int out_size, void* d_ws, size_t ws_size,
                              hipStream_t stream) {
    const float* x   = (const float*)d_in[0];
    const int*   src = (const int*)  d_in[1];
    const int*   dst = (const int*)  d_in[2];
    const float* ew  = (const float*)d_in[3];
    const float* W1  = (const float*)d_in[4];
    const float* b1  = (const float*)d_in[5];
    const float* W2  = (const float*)d_in[6];
    const float* b2  = (const float*)d_in[7];
    const float* W3  = (const float*)d_in[8];
    const float* b3  = (const float*)d_in[9];
    float* out = (float*)d_out;

    // ---- workspace layout (~65 MB) ----
    unsigned short* Hb  = (unsigned short*)d_ws;                 // 25.6 MB
    unsigned short* Ab  = Hb + (size_t)N_NODES * 128;            // 25.6 MB
    unsigned short* Wb1 = Ab + (size_t)N_NODES * 128;            // 64 KB
    unsigned short* Wb2 = Wb1 + 256 * 128;                       // 32 KB
    unsigned short* Wb3 = Wb2 + 128 * 128;                       // 16 KB
    int2*  edges = (int2*)(Wb3 + 64 * 128);                      // 12.8 MB (8B-aligned)
    int*   deg  = (int*)(edges + N_EDGES);                       // 400 KB
    int*   off  = deg + N_NODES;
    int*   cur  = off + N_NODES;
    int*   tot  = cur + N_NODES;                                 // 4 B

    const int eblocks = (N_EDGES + 255) / 256;     // 6250
    const int nblocks = (N_NODES + 255) / 256;     // 391
    const int gblocks = (N_NODES + 127) / 128;     // 782 (GEMM)
    const int ablocks = N_NODES / 4;               // 25000 (gather)

    // ---- CSR build + weight conversion ----
    hipMemsetAsync(deg, 0, ((size_t)3 * N_NODES + 1) * sizeof(int), stream);
    count_kernel<<<eblocks, 256, 0, stream>>>(src, deg);
    alloc_kernel<<<nblocks, 256, 0, stream>>>(deg, off, cur, tot);
    fill_kernel<<<eblocks, 256, 0, stream>>>(src, dst, ew, cur, edges);
    convw_kernel<<<224, 256, 0, stream>>>(W1, W2, W3, Wb1, Wb2, Wb3);

    // ---- Layer 1 ----
    linear_mfma<256, 128, true><<<gblocks, 256, 0, stream>>>(x, Wb1, b1, Hb);
    gather_kernel<128, true, true><<<ablocks, 256, 0, stream>>>(Hb, off, cur, edges, Ab);

    // ---- Layer 2 ----
    linear_mfma<128, 128, false><<<gblocks, 256, 0, stream>>>(Ab, Wb2, b2, Hb);
    gather_kernel<128, true, true><<<ablocks, 256, 0, stream>>>(Hb, off, cur, edges, Ab);

    // ---- Layer 3 ----
    linear_mfma<128, 64, false><<<gblocks, 256, 0, stream>>>(Ab, Wb3, b3, Hb);
    gather_kernel<64, false, false><<<ablocks, 256, 0, stream>>>(Hb, off, cur, edges, out);
}

// Round 9
// 624.952 us; speedup vs baseline: 15.0174x; 1.0555x over previous
//
#include <hip/hip_runtime.h>
#include <hip/hip_bf16.h>
#include <math.h>

#define N_NODES 100000
#define N_EDGES 1600000

typedef __attribute__((ext_vector_type(8))) short bf16x8;
typedef __attribute__((ext_vector_type(4))) float f32x4;

__device__ __forceinline__ float elu_f(float v) {
    return v > 0.0f ? v : (__expf(v) - 1.0f);
}
// f32 -> bf16 bits, round-to-nearest-even
__device__ __forceinline__ short f2bf(float f) {
    unsigned u = __float_as_uint(f);
    u += 0x7fffu + ((u >> 16) & 1u);
    return (short)(u >> 16);
}

// ---------------------------------------------------------------------------
// CSR build: deg counts -> segment alloc (wave scan + 1 atomic/wave) -> fill.
// Edge record packed to 4B: [31:17] = bf16(w) without sign (w in [0,1)),
// [16:0] = dst (< 2^17). Halves fill write payload + gather edge stream.
// ---------------------------------------------------------------------------
__global__ __launch_bounds__(256) void count_kernel(
    const int* __restrict__ src, int* __restrict__ deg)
{
    const int e = blockIdx.x * 256 + threadIdx.x;
    if (e < N_EDGES) atomicAdd(&deg[src[e]], 1);
}

__global__ __launch_bounds__(256) void alloc_kernel(
    const int* __restrict__ deg, int* __restrict__ off,
    int* __restrict__ cur, int* __restrict__ total)
{
    const int n    = blockIdx.x * 256 + threadIdx.x;
    const int lane = threadIdx.x & 63;
    const int v    = (n < N_NODES) ? deg[n] : 0;

    int inc = v;
    #pragma unroll
    for (int s = 1; s < 64; s <<= 1) {
        int t = __shfl_up(inc, s);
        if (lane >= s) inc += t;
    }
    const int wtot = __shfl(inc, 63);
    int base = 0;
    if (lane == 63) base = atomicAdd(total, wtot);
    base = __shfl(base, 63);

    if (n < N_NODES) {
        const int o = base + inc - v;
        off[n] = o;
        cur[n] = o;
    }
}

__global__ __launch_bounds__(256) void fill_kernel(
    const int* __restrict__ src, const int* __restrict__ dst,
    const float* __restrict__ ew, int* __restrict__ cur,
    unsigned* __restrict__ edges)
{
    const int e = blockIdx.x * 256 + threadIdx.x;
    if (e >= N_EDGES) return;
    const int s = src[e];
    // w in [0,1): sign 0. RNE to bf16, keep 15 bits (exp+mantissa).
    const unsigned wb  = __float_as_uint(ew[e]);
    const unsigned w15 = ((wb + 0x7fffu + ((wb >> 16) & 1u)) >> 16) & 0x7fffu;
    const unsigned rec = (w15 << 17) | (unsigned)dst[e];
    const int p = atomicAdd(&cur[s], 1);
    __builtin_nontemporal_store(rec, &edges[p]);   // evict-first: scattered 4B
}

// ---------------------------------------------------------------------------
// Weight conversion f32 -> bf16 (once per call; 57344 elements total).
// ---------------------------------------------------------------------------
__global__ __launch_bounds__(256) void convw_kernel(
    const float* __restrict__ W1, const float* __restrict__ W2,
    const float* __restrict__ W3, unsigned short* __restrict__ Wb1,
    unsigned short* __restrict__ Wb2, unsigned short* __restrict__ Wb3)
{
    const int i = blockIdx.x * 256 + threadIdx.x;
    if (i < 32768)      Wb1[i]         = (unsigned short)f2bf(W1[i]);
    else if (i < 49152) Wb2[i - 32768] = (unsigned short)f2bf(W2[i - 32768]);
    else if (i < 57344) Wb3[i - 49152] = (unsigned short)f2bf(W3[i - 49152]);
}

// ---------------------------------------------------------------------------
// MFMA linear: H_bf16[N, FO] = X[N, K] @ Wb[FO, K]^T + bias.  (unchanged)
// ---------------------------------------------------------------------------
template<int K, int FO, bool A_F32>
__global__ __launch_bounds__(256) void linear_mfma(
    const void* __restrict__ Xin, const unsigned short* __restrict__ Wb,
    const float* __restrict__ bias, unsigned short* __restrict__ H)
{
    constexpr int CT = FO / 16;   // col tiles
    constexpr int KK = K / 32;    // k chunks
    const int tid  = threadIdx.x;
    const int wid  = tid >> 6;
    const int lane = tid & 63;
    const int l15  = lane & 15;
    const int lg   = lane >> 4;
    const int row0 = blockIdx.x * 128 + wid * 32;
    const int kbase = lg * 8;

    f32x4 acc[2][CT];
    #pragma unroll
    for (int c = 0; c < CT; ++c) {
        const float bv = bias[c * 16 + l15];
        #pragma unroll
        for (int r = 0; r < 2; ++r) acc[r][c] = (f32x4){bv, bv, bv, bv};
    }

    #pragma unroll
    for (int kk = 0; kk < KK; ++kk) {
        bf16x8 a[2];
        #pragma unroll
        for (int r = 0; r < 2; ++r) {
            int row = row0 + r * 16 + l15;
            row = row < N_NODES ? row : N_NODES - 1;   // clamp: loads stay in-bounds
            if (A_F32) {
                const float* ap = (const float*)Xin + (size_t)row * K + kk * 32 + kbase;
                const float4 x0 = ((const float4*)ap)[0];
                const float4 x1 = ((const float4*)ap)[1];
                bf16x8 t;
                t[0] = f2bf(x0.x); t[1] = f2bf(x0.y); t[2] = f2bf(x0.z); t[3] = f2bf(x0.w);
                t[4] = f2bf(x1.x); t[5] = f2bf(x1.y); t[6] = f2bf(x1.z); t[7] = f2bf(x1.w);
                a[r] = t;
            } else {
                a[r] = *(const bf16x8*)((const unsigned short*)Xin +
                                        (size_t)row * K + kk * 32 + kbase);
            }
        }
        #pragma unroll
        for (int c = 0; c < CT; ++c) {
            const bf16x8 bfr = *(const bf16x8*)(Wb + (size_t)(c * 16 + l15) * K +
                                                kk * 32 + kbase);
            #pragma unroll
            for (int r = 0; r < 2; ++r)
                acc[r][c] = __builtin_amdgcn_mfma_f32_16x16x32_bf16(
                    a[r], bfr, acc[r][c], 0, 0, 0);
        }
    }

    #pragma unroll
    for (int r = 0; r < 2; ++r) {
        const int rbase = row0 + r * 16 + lg * 4;
        #pragma unroll
        for (int j = 0; j < 4; ++j) {
            const int row = rbase + j;
            if (row < N_NODES) {
                #pragma unroll
                for (int c = 0; c < CT; ++c)
                    H[(size_t)row * FO + c * 16 + l15] =
                        (unsigned short)f2bf(acc[r][c][j]);
            }
        }
    }
}

// ---------------------------------------------------------------------------
// Gather-aggregate over CSR: out[n,:] = sum_{e in seg(n)} H[dst(e),:] * w(e).
// One wave per node. Fully predicated batches of 8: 8 independent H-row
// loads in flight (latency hiding), no serial remainder tail.
// ---------------------------------------------------------------------------
template<int F, bool ELU_OUT, bool OUT_BF16>
__global__ __launch_bounds__(256) void gather_kernel(
    const unsigned short* __restrict__ H, const int* __restrict__ off,
    const int* __restrict__ end, const unsigned* __restrict__ edges,
    void* __restrict__ out)
{
    const int node = (blockIdx.x * 256 + threadIdx.x) >> 6;
    const int lane = threadIdx.x & 63;
    const int beg = off[node];
    const int fin = end[node];

    if (F == 128) {
        float acc0 = 0.f, acc1 = 0.f;
        const unsigned* __restrict__ Hu = (const unsigned*)H + lane;
        for (int e = beg; e < fin; e += 8) {
            unsigned rec[8]; float w[8];
            #pragma unroll
            for (int u = 0; u < 8; ++u) {
                const int  idx = e + u;
                const bool ok  = idx < fin;
                rec[u] = edges[ok ? idx : fin - 1];
                w[u]   = ok ? __uint_as_float((rec[u] >> 17) << 16) : 0.f;
            }
            unsigned v[8];
            #pragma unroll
            for (int u = 0; u < 8; ++u)
                v[u] = Hu[(size_t)(rec[u] & 0x1FFFFu) * 64];
            #pragma unroll
            for (int u = 0; u < 8; ++u) {
                acc0 = fmaf(__uint_as_float(v[u] << 16), w[u], acc0);
                acc1 = fmaf(__uint_as_float(v[u] & 0xffff0000u), w[u], acc1);
            }
        }
        if (ELU_OUT) { acc0 = elu_f(acc0); acc1 = elu_f(acc1); }
        if (OUT_BF16) {
            const unsigned lo = (unsigned short)f2bf(acc0);
            const unsigned hi = (unsigned short)f2bf(acc1);
            ((unsigned*)out)[(size_t)node * 64 + lane] = lo | (hi << 16);
        } else {
            float2 o; o.x = acc0; o.y = acc1;
            ((float2*)out)[(size_t)node * 64 + lane] = o;
        }
    } else {
        float acc = 0.f;
        const unsigned short* __restrict__ Hs = H + lane;
        for (int e = beg; e < fin; e += 8) {
            unsigned rec[8]; float w[8];
            #pragma unroll
            for (int u = 0; u < 8; ++u) {
                const int  idx = e + u;
                const bool ok  = idx < fin;
                rec[u] = edges[ok ? idx : fin - 1];
                w[u]   = ok ? __uint_as_float((rec[u] >> 17) << 16) : 0.f;
            }
            unsigned v[8];
            #pragma unroll
            for (int u = 0; u < 8; ++u)
                v[u] = Hs[(size_t)(rec[u] & 0x1FFFFu) * 64];
            #pragma unroll
            for (int u = 0; u < 8; ++u)
                acc = fmaf(__uint_as_float(v[u] << 16), w[u], acc);
        }
        ((float*)out)[(size_t)node * 64 + lane] = acc;
    }
}

extern "C" void kernel_launch(void* const* d_in, const int* in_sizes, int n_in,
                              void* d_out, int out_size, void* d_ws, size_t ws_size,
                              hipStream_t stream) {
    const float* x   = (const float*)d_in[0];
    const int*   src = (const int*)  d_in[1];
    const int*   dst = (const int*)  d_in[2];
    const float* ew  = (const float*)d_in[3];
    const float* W1  = (const float*)d_in[4];
    const float* b1  = (const float*)d_in[5];
    const float* W2  = (const float*)d_in[6];
    const float* b2  = (const float*)d_in[7];
    const float* W3  = (const float*)d_in[8];
    const float* b3  = (const float*)d_in[9];
    float* out = (float*)d_out;

    // ---- workspace layout (~59 MB) ----
    unsigned short* Hb  = (unsigned short*)d_ws;                 // 25.6 MB
    unsigned short* Ab  = Hb + (size_t)N_NODES * 128;            // 25.6 MB
    unsigned short* Wb1 = Ab + (size_t)N_NODES * 128;            // 64 KB
    unsigned short* Wb2 = Wb1 + 256 * 128;                       // 32 KB
    unsigned short* Wb3 = Wb2 + 128 * 128;                       // 16 KB
    unsigned* edges = (unsigned*)(Wb3 + 64 * 128);               // 6.4 MB
    int*   deg  = (int*)(edges + N_EDGES);                       // 400 KB
    int*   off  = deg + N_NODES;
    int*   cur  = off + N_NODES;
    int*   tot  = cur + N_NODES;                                 // 4 B

    const int eblocks = (N_EDGES + 255) / 256;     // 6250
    const int nblocks = (N_NODES + 255) / 256;     // 391
    const int gblocks = (N_NODES + 127) / 128;     // 782 (GEMM)
    const int ablocks = N_NODES / 4;               // 25000 (gather)

    // ---- CSR build + weight conversion ----
    hipMemsetAsync(deg, 0, ((size_t)3 * N_NODES + 1) * sizeof(int), stream);
    count_kernel<<<eblocks, 256, 0, stream>>>(src, deg);
    alloc_kernel<<<nblocks, 256, 0, stream>>>(deg, off, cur, tot);
    fill_kernel<<<eblocks, 256, 0, stream>>>(src, dst, ew, cur, edges);
    convw_kernel<<<224, 256, 0, stream>>>(W1, W2, W3, Wb1, Wb2, Wb3);

    // ---- Layer 1 ----
    linear_mfma<256, 128, true><<<gblocks, 256, 0, stream>>>(x, Wb1, b1, Hb);
    gather_kernel<128, true, true><<<ablocks, 256, 0, stream>>>(Hb, off, cur, edges, Ab);

    // ---- Layer 2 ----
    linear_mfma<128, 128, false><<<gblocks, 256, 0, stream>>>(Ab, Wb2, b2, Hb);
    gather_kernel<128, true, true><<<ablocks, 256, 0, stream>>>(Hb, off, cur, edges, Ab);

    // ---- Layer 3 ----
    linear_mfma<128, 64, false><<<gblocks, 256, 0, stream>>>(Ab, Wb3, b3, Hb);
    gather_kernel<64, false, false><<<ablocks, 256, 0, stream>>>(Hb, off, cur, edges, out);
}

// Round 11
// 468.944 us; speedup vs baseline: 20.0134x; 1.3327x over previous
//
#include <hip/hip_runtime.h>
#include <hip/hip_bf16.h>
#include <math.h>

#define N_NODES 100000
#define N_EDGES 1600000
#define NB      391          // ceil(N_NODES/256) buckets (src>>8)
#define PBLK    256          // partition blocks
#define CHUNK   6250         // edges per partition block (256*6250 = 1.6M exact)

typedef __attribute__((ext_vector_type(8))) short bf16x8;
typedef __attribute__((ext_vector_type(4))) float f32x4;

__device__ __forceinline__ float elu_f(float v) {
    return v > 0.0f ? v : (__expf(v) - 1.0f);
}
// f32 -> bf16 bits, round-to-nearest-even
__device__ __forceinline__ short f2bf(float f) {
    unsigned u = __float_as_uint(f);
    u += 0x7fffu + ((u >> 16) & 1u);
    return (short)(u >> 16);
}

// ---------------------------------------------------------------------------
// CSR build, bucket-partitioned (no global atomics, line-local writes):
// P1 per-chunk histogram -> P2 scans -> P3 place into bucket runs (8B recs)
// -> P4 per-bucket counting sort to final 4B recs + off/end.
// Edge record 4B: [31:17]=bf16(w) sans sign (w in [0,1)), [16:0]=dst.
// ---------------------------------------------------------------------------
__global__ __launch_bounds__(256) void p1_hist(
    const int* __restrict__ src, unsigned* __restrict__ blkhist /*[NB][PBLK]*/)
{
    __shared__ unsigned hist[NB];
    for (int b = threadIdx.x; b < NB; b += 256) hist[b] = 0;
    __syncthreads();
    const int base = blockIdx.x * CHUNK;
    for (int i = threadIdx.x; i < CHUNK; i += 256)
        atomicAdd(&hist[src[base + i] >> 8], 1u);
    __syncthreads();
    for (int b = threadIdx.x; b < NB; b += 256)
        blkhist[b * PBLK + blockIdx.x] = hist[b];
}

// per-bucket exclusive scan over the 256 blocks (in-place), totals out.
__global__ __launch_bounds__(64) void p2a_scan(
    unsigned* __restrict__ blkhist, unsigned* __restrict__ totals)
{
    const int b = blockIdx.x, l = threadIdx.x;
    unsigned* row = blkhist + b * PBLK;
    unsigned v[4];
    #pragma unroll
    for (int k = 0; k < 4; ++k) v[k] = row[l * 4 + k];
    const unsigned lsum = v[0] + v[1] + v[2] + v[3];
    unsigned inc = lsum;
    #pragma unroll
    for (int s = 1; s < 64; s <<= 1) {
        unsigned t = __shfl_up(inc, s);
        if (l >= s) inc += t;
    }
    unsigned run = inc - lsum;           // exclusive base for this lane
    #pragma unroll
    for (int k = 0; k < 4; ++k) { unsigned t = v[k]; row[l * 4 + k] = run; run += t; }
    if (l == 63) totals[b] = inc;
}

// exclusive scan over bucket totals -> boff[NB+1]
__global__ __launch_bounds__(64) void p2b_scan(
    const unsigned* __restrict__ totals, unsigned* __restrict__ boff)
{
    const int l = threadIdx.x;
    unsigned carry = 0;
    if (l == 0) boff[0] = 0;
    for (int c = 0; c < NB; c += 64) {
        const int i = c + l;
        unsigned v = (i < NB) ? totals[i] : 0;
        unsigned inc = v;
        #pragma unroll
        for (int s = 1; s < 64; s <<= 1) {
            unsigned t = __shfl_up(inc, s);
            if (l >= s) inc += t;
        }
        if (i < NB) boff[i + 1] = carry + inc;
        carry += __shfl(inc, 63);
    }
}

__global__ __launch_bounds__(256) void p3_place(
    const int* __restrict__ src, const int* __restrict__ dst,
    const float* __restrict__ ew, const unsigned* __restrict__ blkhist,
    const unsigned* __restrict__ boff, uint2* __restrict__ mid)
{
    __shared__ unsigned cur[NB];
    for (int b = threadIdx.x; b < NB; b += 256)
        cur[b] = boff[b] + blkhist[b * PBLK + blockIdx.x];
    __syncthreads();
    const int base = blockIdx.x * CHUNK;
    for (int i = threadIdx.x; i < CHUNK; i += 256) {
        const int e = base + i;
        const int s = src[e];
        const unsigned wb  = __float_as_uint(ew[e]);
        const unsigned w15 = ((wb + 0x7fffu + ((wb >> 16) & 1u)) >> 16) & 0x7fffu;
        const unsigned rec = (w15 << 17) | (unsigned)dst[e];
        const unsigned slot = atomicAdd(&cur[s >> 8], 1u);   // LDS atomic
        mid[slot] = make_uint2(rec, (unsigned)s);
    }
}

// one workgroup per bucket: counting-sort region by node, write final recs + off/end
__global__ __launch_bounds__(256) void p4_final(
    const uint2* __restrict__ mid, const unsigned* __restrict__ boff,
    unsigned* __restrict__ edges, int* __restrict__ off, int* __restrict__ end_)
{
    __shared__ unsigned h[256];
    __shared__ unsigned c[256];
    const int b = blockIdx.x, j = threadIdx.x;
    const unsigned r0 = boff[b], r1 = boff[b + 1];

    h[j] = 0;
    __syncthreads();
    for (unsigned r = r0 + j; r < r1; r += 256)
        atomicAdd(&h[mid[r].y & 255u], 1u);
    __syncthreads();
    const unsigned cnt = h[j];
    // Hillis-Steele inclusive scan over h[256]
    for (int o = 1; o < 256; o <<= 1) {
        const unsigned t = (j >= o) ? h[j - o] : 0;
        __syncthreads();
        h[j] += t;
        __syncthreads();
    }
    const unsigned excl = h[j] - cnt;
    c[j] = excl;
    const int node = b * 256 + j;
    if (node < N_NODES) {
        off[node]  = (int)(r0 + excl);
        end_[node] = (int)(r0 + excl + cnt);
    }
    __syncthreads();
    for (unsigned r = r0 + j; r < r1; r += 256) {
        const uint2 m = mid[r];
        const unsigned slot = atomicAdd(&c[m.y & 255u], 1u);
        edges[r0 + slot] = m.x;
    }
}

// ---------------------------------------------------------------------------
// Weight conversion f32 -> bf16 (once per call; 57344 elements total).
// ---------------------------------------------------------------------------
__global__ __launch_bounds__(256) void convw_kernel(
    const float* __restrict__ W1, const float* __restrict__ W2,
    const float* __restrict__ W3, unsigned short* __restrict__ Wb1,
    unsigned short* __restrict__ Wb2, unsigned short* __restrict__ Wb3)
{
    const int i = blockIdx.x * 256 + threadIdx.x;
    if (i < 32768)      Wb1[i]         = (unsigned short)f2bf(W1[i]);
    else if (i < 49152) Wb2[i - 32768] = (unsigned short)f2bf(W2[i - 32768]);
    else if (i < 57344) Wb3[i - 49152] = (unsigned short)f2bf(W3[i - 49152]);
}

// ---------------------------------------------------------------------------
// MFMA linear: H_bf16[N, FO] = X[N, K] @ Wb[FO, K]^T + bias.  (unchanged)
// ---------------------------------------------------------------------------
template<int K, int FO, bool A_F32>
__global__ __launch_bounds__(256) void linear_mfma(
    const void* __restrict__ Xin, const unsigned short* __restrict__ Wb,
    const float* __restrict__ bias, unsigned short* __restrict__ H)
{
    constexpr int CT = FO / 16;
    constexpr int KK = K / 32;
    const int tid  = threadIdx.x;
    const int wid  = tid >> 6;
    const int lane = tid & 63;
    const int l15  = lane & 15;
    const int lg   = lane >> 4;
    const int row0 = blockIdx.x * 128 + wid * 32;
    const int kbase = lg * 8;

    f32x4 acc[2][CT];
    #pragma unroll
    for (int c = 0; c < CT; ++c) {
        const float bv = bias[c * 16 + l15];
        #pragma unroll
        for (int r = 0; r < 2; ++r) acc[r][c] = (f32x4){bv, bv, bv, bv};
    }

    #pragma unroll
    for (int kk = 0; kk < KK; ++kk) {
        bf16x8 a[2];
        #pragma unroll
        for (int r = 0; r < 2; ++r) {
            int row = row0 + r * 16 + l15;
            row = row < N_NODES ? row : N_NODES - 1;
            if (A_F32) {
                const float* ap = (const float*)Xin + (size_t)row * K + kk * 32 + kbase;
                const float4 x0 = ((const float4*)ap)[0];
                const float4 x1 = ((const float4*)ap)[1];
                bf16x8 t;
                t[0] = f2bf(x0.x); t[1] = f2bf(x0.y); t[2] = f2bf(x0.z); t[3] = f2bf(x0.w);
                t[4] = f2bf(x1.x); t[5] = f2bf(x1.y); t[6] = f2bf(x1.z); t[7] = f2bf(x1.w);
                a[r] = t;
            } else {
                a[r] = *(const bf16x8*)((const unsigned short*)Xin +
                                        (size_t)row * K + kk * 32 + kbase);
            }
        }
        #pragma unroll
        for (int c = 0; c < CT; ++c) {
            const bf16x8 bfr = *(const bf16x8*)(Wb + (size_t)(c * 16 + l15) * K +
                                                kk * 32 + kbase);
            #pragma unroll
            for (int r = 0; r < 2; ++r)
                acc[r][c] = __builtin_amdgcn_mfma_f32_16x16x32_bf16(
                    a[r], bfr, acc[r][c], 0, 0, 0);
        }
    }

    #pragma unroll
    for (int r = 0; r < 2; ++r) {
        const int rbase = row0 + r * 16 + lg * 4;
        #pragma unroll
        for (int j = 0; j < 4; ++j) {
            const int row = rbase + j;
            if (row < N_NODES) {
                #pragma unroll
                for (int c = 0; c < CT; ++c)
                    H[(size_t)row * FO + c * 16 + l15] =
                        (unsigned short)f2bf(acc[r][c][j]);
            }
        }
    }
}

// ---------------------------------------------------------------------------
// Gather-aggregate over CSR (unchanged from round 9): predicated batches of 8.
// ---------------------------------------------------------------------------
template<int F, bool ELU_OUT, bool OUT_BF16>
__global__ __launch_bounds__(256) void gather_kernel(
    const unsigned short* __restrict__ H, const int* __restrict__ off,
    const int* __restrict__ end, const unsigned* __restrict__ edges,
    void* __restrict__ out)
{
    const int node = (blockIdx.x * 256 + threadIdx.x) >> 6;
    const int lane = threadIdx.x & 63;
    const int beg = off[node];
    const int fin = end[node];

    if (F == 128) {
        float acc0 = 0.f, acc1 = 0.f;
        const unsigned* __restrict__ Hu = (const unsigned*)H + lane;
        for (int e = beg; e < fin; e += 8) {
            unsigned rec[8]; float w[8];
            #pragma unroll
            for (int u = 0; u < 8; ++u) {
                const int  idx = e + u;
                const bool ok  = idx < fin;
                rec[u] = edges[ok ? idx : fin - 1];
                w[u]   = ok ? __uint_as_float((rec[u] >> 17) << 16) : 0.f;
            }
            unsigned v[8];
            #pragma unroll
            for (int u = 0; u < 8; ++u)
                v[u] = Hu[(size_t)(rec[u] & 0x1FFFFu) * 64];
            #pragma unroll
            for (int u = 0; u < 8; ++u) {
                acc0 = fmaf(__uint_as_float(v[u] << 16), w[u], acc0);
                acc1 = fmaf(__uint_as_float(v[u] & 0xffff0000u), w[u], acc1);
            }
        }
        if (ELU_OUT) { acc0 = elu_f(acc0); acc1 = elu_f(acc1); }
        if (OUT_BF16) {
            const unsigned lo = (unsigned short)f2bf(acc0);
            const unsigned hi = (unsigned short)f2bf(acc1);
            ((unsigned*)out)[(size_t)node * 64 + lane] = lo | (hi << 16);
        } else {
            float2 o; o.x = acc0; o.y = acc1;
            ((float2*)out)[(size_t)node * 64 + lane] = o;
        }
    } else {
        float acc = 0.f;
        const unsigned short* __restrict__ Hs = H + lane;
        for (int e = beg; e < fin; e += 8) {
            unsigned rec[8]; float w[8];
            #pragma unroll
            for (int u = 0; u < 8; ++u) {
                const int  idx = e + u;
                const bool ok  = idx < fin;
                rec[u] = edges[ok ? idx : fin - 1];
                w[u]   = ok ? __uint_as_float((rec[u] >> 17) << 16) : 0.f;
            }
            unsigned v[8];
            #pragma unroll
            for (int u = 0; u < 8; ++u)
                v[u] = Hs[(size_t)(rec[u] & 0x1FFFFu) * 64];
            #pragma unroll
            for (int u = 0; u < 8; ++u)
                acc = fmaf(__uint_as_float(v[u] << 16), w[u], acc);
        }
        ((float*)out)[(size_t)node * 64 + lane] = acc;
    }
}

extern "C" void kernel_launch(void* const* d_in, const int* in_sizes, int n_in,
                              void* d_out, int out_size, void* d_ws, size_t ws_size,
                              hipStream_t stream) {
    const float* x   = (const float*)d_in[0];
    const int*   src = (const int*)  d_in[1];
    const int*   dst = (const int*)  d_in[2];
    const float* ew  = (const float*)d_in[3];
    const float* W1  = (const float*)d_in[4];
    const float* b1  = (const float*)d_in[5];
    const float* W2  = (const float*)d_in[6];
    const float* b2  = (const float*)d_in[7];
    const float* W3  = (const float*)d_in[8];
    const float* b3  = (const float*)d_in[9];
    float* out = (float*)d_out;

    // ---- workspace layout (~72 MB), all arrays fully written before read ----
    char* p = (char*)d_ws;
    unsigned short* Hb  = (unsigned short*)p;  p += (size_t)N_NODES * 128 * 2;  // 25.6 MB
    unsigned short* Ab  = (unsigned short*)p;  p += (size_t)N_NODES * 128 * 2;  // 25.6 MB
    unsigned short* Wb1 = (unsigned short*)p;  p += 256 * 128 * 2;
    unsigned short* Wb2 = (unsigned short*)p;  p += 128 * 128 * 2;
    unsigned short* Wb3 = (unsigned short*)p;  p += 64 * 128 * 2;
    unsigned* edges = (unsigned*)p;            p += (size_t)N_EDGES * 4;        // 6.4 MB
    uint2*    mid   = (uint2*)p;               p += (size_t)N_EDGES * 8;        // 12.8 MB
    unsigned* blkhist = (unsigned*)p;          p += (size_t)NB * PBLK * 4;      // 400 KB
    unsigned* totals  = (unsigned*)p;          p += NB * 4;
    unsigned* boff    = (unsigned*)p;          p += (NB + 1) * 4;
    int* off  = (int*)p;                       p += N_NODES * 4;
    int* end_ = (int*)p;                       p += N_NODES * 4;

    const int gblocks = (N_NODES + 127) / 128;     // 782 (GEMM)
    const int ablocks = N_NODES / 4;               // 25000 (gather)

    // ---- CSR build (bucket partition) + weight conversion ----
    p1_hist<<<PBLK, 256, 0, stream>>>(src, blkhist);
    p2a_scan<<<NB, 64, 0, stream>>>(blkhist, totals);
    p2b_scan<<<1, 64, 0, stream>>>(totals, boff);
    p3_place<<<PBLK, 256, 0, stream>>>(src, dst, ew, blkhist, boff, mid);
    p4_final<<<NB, 256, 0, stream>>>(mid, boff, edges, off, end_);
    convw_kernel<<<224, 256, 0, stream>>>(W1, W2, W3, Wb1, Wb2, Wb3);

    // ---- Layer 1 ----
    linear_mfma<256, 128, true><<<gblocks, 256, 0, stream>>>(x, Wb1, b1, Hb);
    gather_kernel<128, true, true><<<ablocks, 256, 0, stream>>>(Hb, off, end_, edges, Ab);

    // ---- Layer 2 ----
    linear_mfma<128, 128, false><<<gblocks, 256, 0, stream>>>(Ab, Wb2, b2, Hb);
    gather_kernel<128, true, true><<<ablocks, 256, 0, stream>>>(Hb, off, end_, edges, Ab);

    // ---- Layer 3 ----
    linear_mfma<128, 64, false><<<gblocks, 256, 0, stream>>>(Ab, Wb3, b3, Hb);
    gather_kernel<64, false, false><<<ablocks, 256, 0, stream>>>(Hb, off, end_, edges, out);
}